// Round 1
// baseline (529.773 us; speedup 1.0000x reference)
//
#include <hip/hip_runtime.h>

// ---------------------------------------------------------------------------
// TransformerBlockQuantum: B=2,S=2048,E=1024,H=32,DK=32,FFN=4096
// All GEMMs in bf16 MFMA (16x16x32), fp32 accum. Flash attention fused.
// ws layout (MB):
//  [0,2)WqT [2,4)WkT [4,6)WvT [6,8)WoT [8,16)W1T [16,24)W2T
//  [24,40) r1 (fp32 residual1 / post-LN1 fp32)
//  [40,48) xb  | [48,56) qh | [56,64) kh | [64,72) vh   <- hf (32MB) aliases [40,72)
//  [72,80) ao  | [80,88) x1b                             <- r2 (16MB) aliases [72,88)
// ---------------------------------------------------------------------------

typedef unsigned short u16;
typedef __bf16 bf16x8 __attribute__((ext_vector_type(8)));
typedef float f32x4 __attribute__((ext_vector_type(4)));

__device__ __forceinline__ u16 f2b(float f) {
  union { float f; unsigned u; } x; x.f = f;
  unsigned r = x.u + 0x7FFFu + ((x.u >> 16) & 1u);
  return (u16)(r >> 16);
}

#define GLDS16(gp, lp)                                                         \
  __builtin_amdgcn_global_load_lds(                                            \
      (const __attribute__((address_space(1))) void*)(gp),                     \
      (__attribute__((address_space(3))) void*)(lp), 16, 0, 0)

// ---------------- transpose + cast: W[K][N] f32 -> WT[N][K] bf16 ------------
__global__ __launch_bounds__(256) void transpose_cast(
    const float* __restrict__ W, u16* __restrict__ WT, int K, int N) {
  __shared__ float tile[32][33];
  const int tx = threadIdx.x & 31, ty = threadIdx.x >> 5;
  const int n0 = blockIdx.x * 32, k0 = blockIdx.y * 32;
#pragma unroll
  for (int i = 0; i < 4; ++i)
    tile[ty + 8 * i][tx] = W[(size_t)(k0 + ty + 8 * i) * N + n0 + tx];
  __syncthreads();
#pragma unroll
  for (int i = 0; i < 4; ++i)
    WT[(size_t)(n0 + ty + 8 * i) * K + k0 + tx] = f2b(tile[tx][ty + 8 * i]);
}

// ---------------- cast f32 -> bf16 (4 elems/thread) -------------------------
__global__ __launch_bounds__(256) void cast_b(const float* __restrict__ x,
                                              u16* __restrict__ y) {
  int i = blockIdx.x * 256 + threadIdx.x;
  float4 v = ((const float4*)x)[i];
  ushort4 o;
  o.x = f2b(v.x); o.y = f2b(v.y); o.z = f2b(v.z); o.w = f2b(v.w);
  ((ushort4*)y)[i] = o;
}

// ---------------- GEMM: C = A[M,K] @ BT[N,K]^T, bf16 in, fused epilogues ----
// MODE 0: q-proj  -> (acc+bias)*kernelW[d,h], head-layout bf16 store
// MODE 1: k/v-proj-> (acc+bias), head-layout bf16 store
// MODE 2: fp32 out = acc + bias + res   (Wo and W2 paths)
// MODE 3: bf16 out = relu(acc + bias)   (W1 path)
template <int MODE>
__global__ __launch_bounds__(256) void gemm128(
    const u16* __restrict__ A, const u16* __restrict__ BT,
    const float* __restrict__ bias, const float* __restrict__ res,
    void* __restrict__ outp, const float* __restrict__ kW, int N_, int K_) {
  __shared__ __align__(16) u16 As[128 * 32];
  __shared__ __align__(16) u16 Bs[128 * 32];
  const int t = threadIdx.x;
  const int lane = t & 63, wid = t >> 6;
  const int m0 = blockIdx.y * 128, n0 = blockIdx.x * 128;
  const int wr = (wid >> 1) * 64, wc = (wid & 1) * 64;
  const int lr = lane & 15, lg = lane >> 4;
  const int K = K_;

  f32x4 acc[4][4] = {};

  const u16* ga0 = A + (size_t)(m0 + (t >> 2)) * K + (t & 3) * 8;
  const u16* ga1 = ga0 + (size_t)64 * K;
  const u16* gb0 = BT + (size_t)(n0 + (t >> 2)) * K + (t & 3) * 8;
  const u16* gb1 = gb0 + (size_t)64 * K;
  char* lA = (char*)As + wid * 1024;
  char* lB = (char*)Bs + wid * 1024;

  const int nk = K >> 5;
  for (int kt = 0; kt < nk; ++kt) {
    __syncthreads();  // prior ds_reads done before overwrite
    GLDS16(ga0, lA); GLDS16(ga1, lA + 4096);
    GLDS16(gb0, lB); GLDS16(gb1, lB + 4096);
    ga0 += 32; ga1 += 32; gb0 += 32; gb1 += 32;
    __syncthreads();  // drains vmcnt(0): staging visible
    bf16x8 af[4], bf[4];
#pragma unroll
    for (int i = 0; i < 4; ++i) {
      af[i] = *(const bf16x8*)((const char*)As + (wr + i * 16 + lr) * 64 + lg * 16);
      bf[i] = *(const bf16x8*)((const char*)Bs + (wc + i * 16 + lr) * 64 + lg * 16);
    }
#pragma unroll
    for (int mi = 0; mi < 4; ++mi)
#pragma unroll
      for (int ni = 0; ni < 4; ++ni)
        acc[mi][ni] = __builtin_amdgcn_mfma_f32_16x16x32_bf16(
            af[mi], bf[ni], acc[mi][ni], 0, 0, 0);
  }

#pragma unroll
  for (int mi = 0; mi < 4; ++mi) {
#pragma unroll
    for (int ni = 0; ni < 4; ++ni) {
      const int row = m0 + wr + mi * 16 + lg * 4;
      const int col = n0 + wc + ni * 16 + lr;
      const float bv = bias[col];
      f32x4 v = acc[mi][ni];
      if constexpr (MODE == 0 || MODE == 1) {
        const int h = col >> 5, d = col & 31;
        const float sc = (MODE == 0) ? kW[d * 32 + h] : 1.0f;
        u16* o = (u16*)outp;
#pragma unroll
        for (int r = 0; r < 4; ++r) {
          const int rr = row + r;
          const int bb = rr >> 11, s = rr & 2047;
          o[(size_t)(((bb * 32 + h) * 2048) + s) * 32 + d] = f2b((v[r] + bv) * sc);
        }
      } else if constexpr (MODE == 2) {
        float* o = (float*)outp;
#pragma unroll
        for (int r = 0; r < 4; ++r) {
          const int rr = row + r;
          o[(size_t)rr * N_ + col] = v[r] + bv + res[(size_t)rr * N_ + col];
        }
      } else {
        u16* o = (u16*)outp;
#pragma unroll
        for (int r = 0; r < 4; ++r) {
          const int rr = row + r;
          float y = v[r] + bv;
          o[(size_t)rr * N_ + col] = f2b(y > 0.f ? y : 0.f);
        }
      }
    }
  }
}

// ---------------- fused flash attention -------------------------------------
// One wave = one (b,h) x 16 queries. scores = (q*kw) @ k^T (no 1/sqrt(dk)).
__global__ __launch_bounds__(256) void attn_kernel(
    const u16* __restrict__ Q, const u16* __restrict__ K,
    const u16* __restrict__ V, u16* __restrict__ O) {
  __shared__ __align__(16) u16 P[4][16 * 32];
  const int t = threadIdx.x, wid = t >> 6, lane = t & 63;
  const int gw = blockIdx.x * 4 + wid;     // 0..8191
  const int qt = gw & 127;                 // S/16 = 128 q-tiles
  const int bh = gw >> 7;                  // 0..63
  const u16* Qh = Q + (size_t)bh * 2048 * 32;
  const u16* Kh = K + (size_t)bh * 2048 * 32;
  const u16* Vh = V + (size_t)bh * 2048 * 32;
  const int q0 = qt * 16;
  const int lr = lane & 15, lg = lane >> 4;

  const bf16x8 qf = *(const bf16x8*)(Qh + (size_t)(q0 + lr) * 32 + lg * 8);
  f32x4 acc0 = {}, acc1 = {};
  float mrun[4] = {-1e30f, -1e30f, -1e30f, -1e30f};
  float lrun[4] = {0.f, 0.f, 0.f, 0.f};
  const f32x4 zero = {};

  for (int j0 = 0; j0 < 2048; j0 += 32) {
    const bf16x8 kf0 = *(const bf16x8*)(Kh + (size_t)(j0 + lr) * 32 + lg * 8);
    const bf16x8 kf1 = *(const bf16x8*)(Kh + (size_t)(j0 + 16 + lr) * 32 + lg * 8);
    f32x4 s0 = __builtin_amdgcn_mfma_f32_16x16x32_bf16(qf, kf0, zero, 0, 0, 0);
    f32x4 s1 = __builtin_amdgcn_mfma_f32_16x16x32_bf16(qf, kf1, zero, 0, 0, 0);

#pragma unroll
    for (int r = 0; r < 4; ++r) {
      float mx = fmaxf(s0[r], s1[r]);
#pragma unroll
      for (int off = 1; off < 16; off <<= 1) mx = fmaxf(mx, __shfl_xor(mx, off));
      const float mn = fmaxf(mrun[r], mx);
      const float al = __expf(mrun[r] - mn);
      const float p0 = __expf(s0[r] - mn);
      const float p1 = __expf(s1[r] - mn);
      float sm = p0 + p1;
#pragma unroll
      for (int off = 1; off < 16; off <<= 1) sm += __shfl_xor(sm, off);
      lrun[r] = lrun[r] * al + sm;
      mrun[r] = mn;
      acc0[r] *= al; acc1[r] *= al;
      P[wid][(lg * 4 + r) * 32 + lr] = f2b(p0);
      P[wid][(lg * 4 + r) * 32 + 16 + lr] = f2b(p1);
    }
    asm volatile("s_waitcnt lgkmcnt(0)" ::: "memory");
    __builtin_amdgcn_sched_barrier(0);
    const bf16x8 pf = *(const bf16x8*)(&P[wid][lr * 32 + lg * 8]);

    union { u16 u[8]; bf16x8 v; } v0, v1;
#pragma unroll
    for (int e = 0; e < 8; ++e) {
      const int j = j0 + lg * 8 + e;
      v0.u[e] = Vh[(size_t)j * 32 + lr];
      v1.u[e] = Vh[(size_t)j * 32 + 16 + lr];
    }
    acc0 = __builtin_amdgcn_mfma_f32_16x16x32_bf16(pf, v0.v, acc0, 0, 0, 0);
    acc1 = __builtin_amdgcn_mfma_f32_16x16x32_bf16(pf, v1.v, acc1, 0, 0, 0);
  }

  const int bb = bh >> 5, h = bh & 31;
#pragma unroll
  for (int r = 0; r < 4; ++r) {
    const int i = q0 + lg * 4 + r;
    const float inv = 1.f / lrun[r];
    u16* o = O + (size_t)(bb * 2048 + i) * 1024 + h * 32;
    o[lr] = f2b(acc0[r] * inv);
    o[16 + lr] = f2b(acc1[r] * inv);
  }
}

// ---------------- LayerNorm (1 wave per row of 1024) ------------------------
template <int WB>
__global__ __launch_bounds__(256) void ln_kernel(
    const float* X, const float* __restrict__ g, const float* __restrict__ b,
    float* outf, u16* __restrict__ outb) {
  const int wid = threadIdx.x >> 6, lane = threadIdx.x & 63;
  const int row = blockIdx.x * 4 + wid;
  const float4* X4 = (const float4*)(X + (size_t)row * 1024);
  float4 xs[4];
  float s = 0.f, sq = 0.f;
#pragma unroll
  for (int i = 0; i < 4; ++i) {
    xs[i] = X4[lane + i * 64];
    s += xs[i].x + xs[i].y + xs[i].z + xs[i].w;
    sq += xs[i].x * xs[i].x + xs[i].y * xs[i].y + xs[i].z * xs[i].z + xs[i].w * xs[i].w;
  }
#pragma unroll
  for (int m = 1; m < 64; m <<= 1) { s += __shfl_xor(s, m); sq += __shfl_xor(sq, m); }
  const float mean = s * (1.f / 1024.f);
  float var = sq * (1.f / 1024.f) - mean * mean;
  var = var > 0.f ? var : 0.f;
  const float rstd = rsqrtf(var + 1e-5f);
  const float4* g4 = (const float4*)g;
  const float4* b4 = (const float4*)b;
  float4* of = (float4*)(outf + (size_t)row * 1024);
#pragma unroll
  for (int i = 0; i < 4; ++i) {
    const int c = lane + i * 64;
    const float4 gv = g4[c], bv = b4[c], x = xs[i];
    float4 y;
    y.x = (x.x - mean) * rstd * gv.x + bv.x;
    y.y = (x.y - mean) * rstd * gv.y + bv.y;
    y.z = (x.z - mean) * rstd * gv.z + bv.z;
    y.w = (x.w - mean) * rstd * gv.w + bv.w;
    of[c] = y;
    if constexpr (WB) {
      ushort4 yb;
      yb.x = f2b(y.x); yb.y = f2b(y.y); yb.z = f2b(y.z); yb.w = f2b(y.w);
      ((ushort4*)(outb + (size_t)row * 1024))[c] = yb;
    }
  }
}

// ---------------------------------------------------------------------------
extern "C" void kernel_launch(void* const* d_in, const int* in_sizes, int n_in,
                              void* d_out, int out_size, void* d_ws,
                              size_t ws_size, hipStream_t stream) {
  const float* x   = (const float*)d_in[0];
  const float* Wq  = (const float*)d_in[1];
  const float* bq  = (const float*)d_in[2];
  const float* Wk  = (const float*)d_in[3];
  const float* bk  = (const float*)d_in[4];
  const float* Wv  = (const float*)d_in[5];
  const float* bv  = (const float*)d_in[6];
  const float* kW  = (const float*)d_in[7];
  const float* Wo  = (const float*)d_in[8];
  const float* bo  = (const float*)d_in[9];
  const float* W1  = (const float*)d_in[10];
  const float* b1  = (const float*)d_in[11];
  const float* W2  = (const float*)d_in[12];
  const float* b2  = (const float*)d_in[13];
  const float* g1  = (const float*)d_in[14];
  const float* be1 = (const float*)d_in[15];
  const float* g2  = (const float*)d_in[16];
  const float* be2 = (const float*)d_in[17];

  char* ws = (char*)d_ws;
  const size_t MB = 1024 * 1024;
  u16*   WqT = (u16*)(ws + 0 * MB);
  u16*   WkT = (u16*)(ws + 2 * MB);
  u16*   WvT = (u16*)(ws + 4 * MB);
  u16*   WoT = (u16*)(ws + 6 * MB);
  u16*   W1T = (u16*)(ws + 8 * MB);
  u16*   W2T = (u16*)(ws + 16 * MB);
  float* r1  = (float*)(ws + 24 * MB);
  u16*   xb  = (u16*)(ws + 40 * MB);
  u16*   qh  = (u16*)(ws + 48 * MB);
  u16*   kh  = (u16*)(ws + 56 * MB);
  u16*   vh  = (u16*)(ws + 64 * MB);
  u16*   hf  = (u16*)(ws + 40 * MB);  // aliases xb..vh (32MB), free by then
  u16*   ao  = (u16*)(ws + 72 * MB);
  u16*   x1b = (u16*)(ws + 80 * MB);
  float* r2  = (float*)(ws + 72 * MB);  // aliases ao+x1b, free by then

  const dim3 blk(256);

  // weights -> bf16 transposed [N][K]
  transpose_cast<<<dim3(32, 32), blk, 0, stream>>>(Wq, WqT, 1024, 1024);
  transpose_cast<<<dim3(32, 32), blk, 0, stream>>>(Wk, WkT, 1024, 1024);
  transpose_cast<<<dim3(32, 32), blk, 0, stream>>>(Wv, WvT, 1024, 1024);
  transpose_cast<<<dim3(32, 32), blk, 0, stream>>>(Wo, WoT, 1024, 1024);
  transpose_cast<<<dim3(128, 32), blk, 0, stream>>>(W1, W1T, 1024, 4096);
  transpose_cast<<<dim3(32, 128), blk, 0, stream>>>(W2, W2T, 4096, 1024);
  // x -> bf16
  cast_b<<<4096, blk, 0, stream>>>(x, xb);

  // QKV projections (q scaled by kernelW, head layout)
  gemm128<0><<<dim3(8, 32), blk, 0, stream>>>(xb, WqT, bq, nullptr, qh, kW, 1024, 1024);
  gemm128<1><<<dim3(8, 32), blk, 0, stream>>>(xb, WkT, bk, nullptr, kh, nullptr, 1024, 1024);
  gemm128<1><<<dim3(8, 32), blk, 0, stream>>>(xb, WvT, bv, nullptr, vh, nullptr, 1024, 1024);

  // fused flash attention
  attn_kernel<<<2048, blk, 0, stream>>>(qh, kh, vh, ao);

  // out-proj + residual -> r1 (fp32)
  gemm128<2><<<dim3(8, 32), blk, 0, stream>>>(ao, WoT, bo, x, r1, nullptr, 1024, 1024);
  // LN1: r1 -> x1b (bf16) and r1 in-place (fp32)
  ln_kernel<1><<<1024, blk, 0, stream>>>(r1, g1, be1, r1, x1b);
  // FFN
  gemm128<3><<<dim3(32, 32), blk, 0, stream>>>(x1b, W1T, b1, nullptr, hf, nullptr, 4096, 1024);
  gemm128<2><<<dim3(8, 32), blk, 0, stream>>>(hf, W2T, b2, r1, r2, nullptr, 1024, 4096);
  // LN2 -> d_out
  ln_kernel<0><<<1024, blk, 0, stream>>>(r2, g2, be2, (float*)d_out, nullptr);

  (void)in_sizes; (void)n_in; (void)out_size; (void)ws_size;
}

// Round 2
// 441.386 us; speedup vs baseline: 1.2002x; 1.2002x over previous
//
#include <hip/hip_runtime.h>

// ---------------------------------------------------------------------------
// TransformerBlockQuantum: B=2,S=2048,E=1024,H=32,DK=32,FFN=4096
// GEMMs: bf16 MFMA 16x16x32, fp32 accum (m97 structure).
// Attention: swapped-QK^T flash, per-lane softmax, K=16 PV MFMAs, no LDS.
// ws layout (MB):
//  [0,2)WqT [2,4)WkT [4,6)WvT [6,8)WoT [8,16)W1T [16,24)W2T
//  [24,40) r1 (fp32 residual1 / post-LN1 fp32)
//  [40,48) xb  | [48,56) qh | [56,64) kh | [64,72) vT   <- hf (32MB) aliases [40,72)
//  [72,80) ao  | [80,88) x1b                             <- r2 (16MB) aliases [72,88)
// ---------------------------------------------------------------------------

typedef unsigned short u16;
typedef __bf16 bf16x8 __attribute__((ext_vector_type(8)));
typedef __bf16 bf16x4 __attribute__((ext_vector_type(4)));
typedef short s16x4 __attribute__((ext_vector_type(4)));
typedef float f32x4 __attribute__((ext_vector_type(4)));

__device__ __forceinline__ u16 f2b(float f) {
  union { float f; unsigned u; } x; x.f = f;
  unsigned r = x.u + 0x7FFFu + ((x.u >> 16) & 1u);
  return (u16)(r >> 16);
}

__device__ __forceinline__ unsigned pkbf(float lo, float hi) {
  unsigned r;
  asm("v_cvt_pk_bf16_f32 %0, %1, %2" : "=v"(r) : "v"(lo), "v"(hi));
  return r;
}

__device__ __forceinline__ f32x4 mfma16(bf16x4 a, bf16x4 b, f32x4 c) {
#if __has_builtin(__builtin_amdgcn_mfma_f32_16x16x16bf16_1k)
  union { bf16x4 b4; s16x4 s4; } ua, ub;
  ua.b4 = a; ub.b4 = b;
  return __builtin_amdgcn_mfma_f32_16x16x16bf16_1k(ua.s4, ub.s4, c, 0, 0, 0);
#else
  asm("v_mfma_f32_16x16x16_bf16 %0, %1, %2, %0" : "+v"(c) : "v"(a), "v"(b));
  return c;
#endif
}

#define GLDS16(gp, lp)                                                         \
  __builtin_amdgcn_global_load_lds(                                            \
      (const __attribute__((address_space(1))) void*)(gp),                     \
      (__attribute__((address_space(3))) void*)(lp), 16, 0, 0)

// ---------------- transpose + cast: W[K][N] f32 -> WT[N][K] bf16 ------------
__global__ __launch_bounds__(256) void transpose_cast(
    const float* __restrict__ W, u16* __restrict__ WT, int K, int N) {
  __shared__ float tile[32][33];
  const int tx = threadIdx.x & 31, ty = threadIdx.x >> 5;
  const int n0 = blockIdx.x * 32, k0 = blockIdx.y * 32;
#pragma unroll
  for (int i = 0; i < 4; ++i)
    tile[ty + 8 * i][tx] = W[(size_t)(k0 + ty + 8 * i) * N + n0 + tx];
  __syncthreads();
#pragma unroll
  for (int i = 0; i < 4; ++i)
    WT[(size_t)(n0 + ty + 8 * i) * K + k0 + tx] = f2b(tile[tx][ty + 8 * i]);
}

// ---------------- cast f32 -> bf16 (4 elems/thread) -------------------------
__global__ __launch_bounds__(256) void cast_b(const float* __restrict__ x,
                                              u16* __restrict__ y) {
  int i = blockIdx.x * 256 + threadIdx.x;
  float4 v = ((const float4*)x)[i];
  ushort4 o;
  o.x = f2b(v.x); o.y = f2b(v.y); o.z = f2b(v.z); o.w = f2b(v.w);
  ((ushort4*)y)[i] = o;
}

// ---------------- GEMM: C = A[M,K] @ BT[N,K]^T, bf16 in, fused epilogues ----
// MODE 0: q-proj  -> (acc+bias)*kernelW[d,h]*log2e, head-layout bf16 store
// MODE 1: k-proj  -> (acc+bias), head-layout bf16 store
// MODE 2: fp32 out = acc + bias + res   (Wo and W2 paths)
// MODE 3: bf16 out = relu(acc + bias)   (W1 path)
// MODE 4: v-proj  -> (acc+bias), TRANSPOSED head layout VT[bh][d][s]
template <int MODE>
__global__ __launch_bounds__(256) void gemm128(
    const u16* __restrict__ A, const u16* __restrict__ BT,
    const float* __restrict__ bias, const float* __restrict__ res,
    void* __restrict__ outp, const float* __restrict__ kW, int N_, int K_) {
  __shared__ __align__(16) u16 As[128 * 32];
  __shared__ __align__(16) u16 Bs[128 * 32];
  const int t = threadIdx.x;
  const int lane = t & 63, wid = t >> 6;
  const int m0 = blockIdx.y * 128, n0 = blockIdx.x * 128;
  const int wr = (wid >> 1) * 64, wc = (wid & 1) * 64;
  const int lr = lane & 15, lg = lane >> 4;
  const int K = K_;

  f32x4 acc[4][4] = {};

  const u16* ga0 = A + (size_t)(m0 + (t >> 2)) * K + (t & 3) * 8;
  const u16* ga1 = ga0 + (size_t)64 * K;
  const u16* gb0 = BT + (size_t)(n0 + (t >> 2)) * K + (t & 3) * 8;
  const u16* gb1 = gb0 + (size_t)64 * K;
  char* lA = (char*)As + wid * 1024;
  char* lB = (char*)Bs + wid * 1024;

  const int nk = K >> 5;
  for (int kt = 0; kt < nk; ++kt) {
    __syncthreads();
    GLDS16(ga0, lA); GLDS16(ga1, lA + 4096);
    GLDS16(gb0, lB); GLDS16(gb1, lB + 4096);
    ga0 += 32; ga1 += 32; gb0 += 32; gb1 += 32;
    __syncthreads();
    bf16x8 af[4], bf[4];
#pragma unroll
    for (int i = 0; i < 4; ++i) {
      af[i] = *(const bf16x8*)((const char*)As + (wr + i * 16 + lr) * 64 + lg * 16);
      bf[i] = *(const bf16x8*)((const char*)Bs + (wc + i * 16 + lr) * 64 + lg * 16);
    }
#pragma unroll
    for (int mi = 0; mi < 4; ++mi)
#pragma unroll
      for (int ni = 0; ni < 4; ++ni)
        acc[mi][ni] = __builtin_amdgcn_mfma_f32_16x16x32_bf16(
            af[mi], bf[ni], acc[mi][ni], 0, 0, 0);
  }

#pragma unroll
  for (int mi = 0; mi < 4; ++mi) {
#pragma unroll
    for (int ni = 0; ni < 4; ++ni) {
      const int row = m0 + wr + mi * 16 + lg * 4;
      const int col = n0 + wc + ni * 16 + lr;
      const float bv = bias[col];
      f32x4 v = acc[mi][ni];
      if constexpr (MODE == 0 || MODE == 1) {
        const int h = col >> 5, d = col & 31;
        const float sc = (MODE == 0) ? kW[d * 32 + h] * 1.44269504089f : 1.0f;
        u16* o = (u16*)outp;
#pragma unroll
        for (int r = 0; r < 4; ++r) {
          const int rr = row + r;
          const int bb = rr >> 11, s = rr & 2047;
          o[(size_t)(((bb * 32 + h) * 2048) + s) * 32 + d] = f2b((v[r] + bv) * sc);
        }
      } else if constexpr (MODE == 2) {
        float* o = (float*)outp;
#pragma unroll
        for (int r = 0; r < 4; ++r) {
          const int rr = row + r;
          o[(size_t)rr * N_ + col] = v[r] + bv + res[(size_t)rr * N_ + col];
        }
      } else if constexpr (MODE == 3) {
        u16* o = (u16*)outp;
#pragma unroll
        for (int r = 0; r < 4; ++r) {
          const int rr = row + r;
          float y = v[r] + bv;
          o[(size_t)rr * N_ + col] = f2b(y > 0.f ? y : 0.f);
        }
      } else {  // MODE 4: VT[bh][d][s], 4 consecutive s -> ushort4
        const int h = col >> 5, d = col & 31;
        const int bb = row >> 11, s0 = row & 2047;
        u16* o = (u16*)outp;
        ushort4 st;
        st.x = f2b(v[0] + bv); st.y = f2b(v[1] + bv);
        st.z = f2b(v[2] + bv); st.w = f2b(v[3] + bv);
        *(ushort4*)(o + ((size_t)((bb * 32 + h) * 32 + d)) * 2048 + s0) = st;
      }
    }
  }
}

// ---------------- swapped-QK^T flash attention ------------------------------
// One wave = one (b,h) x 32 queries. Scores pre-scaled by log2e (in q-proj),
// softmax in exp2. C1[key][q]: each lane holds 16 keys of ONE query (lr).
// PV: O^T = mfma16(VT_frag, P_frag) accumulated in fp32.
__global__ __launch_bounds__(256) void attn_kernel(
    const u16* __restrict__ Q, const u16* __restrict__ K,
    const u16* __restrict__ VT, u16* __restrict__ O) {
  const int t = threadIdx.x, wid = t >> 6;
  const int lane = t & 63;
  // XCD-chunked swizzle: 1024 blocks, 8 XCDs -> 128 contiguous per XCD
  const int bid = blockIdx.x;
  const int swz = (bid & 7) * 128 + (bid >> 3);
  const int gw = swz * 4 + wid;            // 0..4095
  const int qw = gw & 63;                  // 64 q-waves per head
  const int bh = gw >> 6;                  // 0..63
  const int q0 = qw * 32;
  const int lr = lane & 15, lg = lane >> 4;
  const u16* Qh = Q + (size_t)bh * 2048 * 32;
  const u16* Kh = K + (size_t)bh * 2048 * 32;
  const u16* Vh = VT + (size_t)bh * 32 * 2048;

  bf16x8 qf[2];
  qf[0] = *(const bf16x8*)(Qh + (size_t)(q0 + lr) * 32 + lg * 8);
  qf[1] = *(const bf16x8*)(Qh + (size_t)(q0 + 16 + lr) * 32 + lg * 8);

  f32x4 acc[2][2] = {};  // [qh][dc]
  float mrun[2] = {-3e38f, -3e38f};
  float lrun[2] = {0.f, 0.f};
  const f32x4 zero = {};

  for (int j0 = 0; j0 < 2048; j0 += 64) {
    bf16x8 kf[4];
#pragma unroll
    for (int kc = 0; kc < 4; ++kc)
      kf[kc] = *(const bf16x8*)(Kh + (size_t)(j0 + kc * 16 + lr) * 32 + lg * 8);
    bf16x4 vt[2][4];
#pragma unroll
    for (int dc = 0; dc < 2; ++dc)
#pragma unroll
      for (int kc = 0; kc < 4; ++kc)
        vt[dc][kc] = *(const bf16x4*)(Vh + (size_t)(dc * 16 + lr) * 2048 +
                                      j0 + kc * 16 + lg * 4);

    bf16x4 pf[2][4];
    float al[2];
#pragma unroll
    for (int qh = 0; qh < 2; ++qh) {
      f32x4 s[4];
#pragma unroll
      for (int kc = 0; kc < 4; ++kc)
        s[kc] = __builtin_amdgcn_mfma_f32_16x16x32_bf16(kf[kc], qf[qh], zero,
                                                        0, 0, 0);
      float m01 = fmaxf(fmaxf(s[0][0], s[0][1]), fmaxf(s[0][2], s[0][3]));
      float m23 = fmaxf(fmaxf(s[1][0], s[1][1]), fmaxf(s[1][2], s[1][3]));
      float m45 = fmaxf(fmaxf(s[2][0], s[2][1]), fmaxf(s[2][2], s[2][3]));
      float m67 = fmaxf(fmaxf(s[3][0], s[3][1]), fmaxf(s[3][2], s[3][3]));
      float mx = fmaxf(fmaxf(m01, m23), fmaxf(m45, m67));
      mx = fmaxf(mx, __shfl_xor(mx, 16));
      mx = fmaxf(mx, __shfl_xor(mx, 32));
      const float mn = fmaxf(mrun[qh], mx);
      al[qh] = exp2f(mrun[qh] - mn);
      mrun[qh] = mn;
      float sm = 0.f;
#pragma unroll
      for (int kc = 0; kc < 4; ++kc) {
        const float p0 = exp2f(s[kc][0] - mn);
        const float p1 = exp2f(s[kc][1] - mn);
        const float p2 = exp2f(s[kc][2] - mn);
        const float p3 = exp2f(s[kc][3] - mn);
        sm += (p0 + p1) + (p2 + p3);
        union { unsigned u[2]; bf16x4 v; } pc;
        pc.u[0] = pkbf(p0, p1);
        pc.u[1] = pkbf(p2, p3);
        pf[qh][kc] = pc.v;
      }
      sm += __shfl_xor(sm, 16);
      sm += __shfl_xor(sm, 32);
      lrun[qh] = lrun[qh] * al[qh] + sm;
    }
#pragma unroll
    for (int qh = 0; qh < 2; ++qh)
#pragma unroll
      for (int dc = 0; dc < 2; ++dc) {
        f32x4 a = acc[qh][dc];
        a[0] *= al[qh]; a[1] *= al[qh]; a[2] *= al[qh]; a[3] *= al[qh];
#pragma unroll
        for (int kc = 0; kc < 4; ++kc)
          a = mfma16(vt[dc][kc], pf[qh][kc], a);
        acc[qh][dc] = a;
      }
  }

  const int bb = bh >> 5, h = bh & 31;
#pragma unroll
  for (int qh = 0; qh < 2; ++qh) {
    const float inv = 1.f / lrun[qh];
    const int s = q0 + qh * 16 + lr;
    u16* o = O + (size_t)(bb * 2048 + s) * 1024 + h * 32;
#pragma unroll
    for (int dc = 0; dc < 2; ++dc) {
      ushort4 st;
      st.x = f2b(acc[qh][dc][0] * inv);
      st.y = f2b(acc[qh][dc][1] * inv);
      st.z = f2b(acc[qh][dc][2] * inv);
      st.w = f2b(acc[qh][dc][3] * inv);
      *(ushort4*)(o + dc * 16 + lg * 4) = st;
    }
  }
}

// ---------------- LayerNorm (1 wave per row of 1024) ------------------------
template <int WB>
__global__ __launch_bounds__(256) void ln_kernel(
    const float* X, const float* __restrict__ g, const float* __restrict__ b,
    float* outf, u16* __restrict__ outb) {
  const int wid = threadIdx.x >> 6, lane = threadIdx.x & 63;
  const int row = blockIdx.x * 4 + wid;
  const float4* X4 = (const float4*)(X + (size_t)row * 1024);
  float4 xs[4];
  float s = 0.f, sq = 0.f;
#pragma unroll
  for (int i = 0; i < 4; ++i) {
    xs[i] = X4[lane + i * 64];
    s += xs[i].x + xs[i].y + xs[i].z + xs[i].w;
    sq += xs[i].x * xs[i].x + xs[i].y * xs[i].y + xs[i].z * xs[i].z + xs[i].w * xs[i].w;
  }
#pragma unroll
  for (int m = 1; m < 64; m <<= 1) { s += __shfl_xor(s, m); sq += __shfl_xor(sq, m); }
  const float mean = s * (1.f / 1024.f);
  float var = sq * (1.f / 1024.f) - mean * mean;
  var = var > 0.f ? var : 0.f;
  const float rstd = rsqrtf(var + 1e-5f);
  const float4* g4 = (const float4*)g;
  const float4* b4 = (const float4*)b;
  float4* of = (float4*)(outf + (size_t)row * 1024);
#pragma unroll
  for (int i = 0; i < 4; ++i) {
    const int c = lane + i * 64;
    const float4 gv = g4[c], bv = b4[c], x = xs[i];
    float4 y;
    y.x = (x.x - mean) * rstd * gv.x + bv.x;
    y.y = (x.y - mean) * rstd * gv.y + bv.y;
    y.z = (x.z - mean) * rstd * gv.z + bv.z;
    y.w = (x.w - mean) * rstd * gv.w + bv.w;
    of[c] = y;
    if constexpr (WB) {
      ushort4 yb;
      yb.x = f2b(y.x); yb.y = f2b(y.y); yb.z = f2b(y.z); yb.w = f2b(y.w);
      ((ushort4*)(outb + (size_t)row * 1024))[c] = yb;
    }
  }
}

// ---------------------------------------------------------------------------
extern "C" void kernel_launch(void* const* d_in, const int* in_sizes, int n_in,
                              void* d_out, int out_size, void* d_ws,
                              size_t ws_size, hipStream_t stream) {
  const float* x   = (const float*)d_in[0];
  const float* Wq  = (const float*)d_in[1];
  const float* bq  = (const float*)d_in[2];
  const float* Wk  = (const float*)d_in[3];
  const float* bk  = (const float*)d_in[4];
  const float* Wv  = (const float*)d_in[5];
  const float* bv  = (const float*)d_in[6];
  const float* kW  = (const float*)d_in[7];
  const float* Wo  = (const float*)d_in[8];
  const float* bo  = (const float*)d_in[9];
  const float* W1  = (const float*)d_in[10];
  const float* b1  = (const float*)d_in[11];
  const float* W2  = (const float*)d_in[12];
  const float* b2  = (const float*)d_in[13];
  const float* g1  = (const float*)d_in[14];
  const float* be1 = (const float*)d_in[15];
  const float* g2  = (const float*)d_in[16];
  const float* be2 = (const float*)d_in[17];

  char* ws = (char*)d_ws;
  const size_t MB = 1024 * 1024;
  u16*   WqT = (u16*)(ws + 0 * MB);
  u16*   WkT = (u16*)(ws + 2 * MB);
  u16*   WvT = (u16*)(ws + 4 * MB);
  u16*   WoT = (u16*)(ws + 6 * MB);
  u16*   W1T = (u16*)(ws + 8 * MB);
  u16*   W2T = (u16*)(ws + 16 * MB);
  float* r1  = (float*)(ws + 24 * MB);
  u16*   xb  = (u16*)(ws + 40 * MB);
  u16*   qhB = (u16*)(ws + 48 * MB);
  u16*   khB = (u16*)(ws + 56 * MB);
  u16*   vTB = (u16*)(ws + 64 * MB);
  u16*   hf  = (u16*)(ws + 40 * MB);  // aliases xb..vT (32MB), free by then
  u16*   ao  = (u16*)(ws + 72 * MB);
  u16*   x1b = (u16*)(ws + 80 * MB);
  float* r2  = (float*)(ws + 72 * MB);  // aliases ao+x1b, free by then

  const dim3 blk(256);

  transpose_cast<<<dim3(32, 32), blk, 0, stream>>>(Wq, WqT, 1024, 1024);
  transpose_cast<<<dim3(32, 32), blk, 0, stream>>>(Wk, WkT, 1024, 1024);
  transpose_cast<<<dim3(32, 32), blk, 0, stream>>>(Wv, WvT, 1024, 1024);
  transpose_cast<<<dim3(32, 32), blk, 0, stream>>>(Wo, WoT, 1024, 1024);
  transpose_cast<<<dim3(128, 32), blk, 0, stream>>>(W1, W1T, 1024, 4096);
  transpose_cast<<<dim3(32, 128), blk, 0, stream>>>(W2, W2T, 4096, 1024);
  cast_b<<<4096, blk, 0, stream>>>(x, xb);

  // QKV projections: q scaled by kernelW*log2e; v stored transposed
  gemm128<0><<<dim3(8, 32), blk, 0, stream>>>(xb, WqT, bq, nullptr, qhB, kW, 1024, 1024);
  gemm128<1><<<dim3(8, 32), blk, 0, stream>>>(xb, WkT, bk, nullptr, khB, nullptr, 1024, 1024);
  gemm128<4><<<dim3(8, 32), blk, 0, stream>>>(xb, WvT, bv, nullptr, vTB, nullptr, 1024, 1024);

  // fused flash attention (1024 blocks x 4 waves, 32 queries/wave)
  attn_kernel<<<1024, blk, 0, stream>>>(qhB, khB, vTB, ao);

  // out-proj + residual -> r1 (fp32)
  gemm128<2><<<dim3(8, 32), blk, 0, stream>>>(ao, WoT, bo, x, r1, nullptr, 1024, 1024);
  ln_kernel<1><<<1024, blk, 0, stream>>>(r1, g1, be1, r1, x1b);
  // FFN
  gemm128<3><<<dim3(32, 32), blk, 0, stream>>>(x1b, W1T, b1, nullptr, hf, nullptr, 4096, 1024);
  gemm128<2><<<dim3(8, 32), blk, 0, stream>>>(hf, W2T, b2, r1, r2, nullptr, 1024, 4096);
  ln_kernel<0><<<1024, blk, 0, stream>>>(r2, g2, be2, (float*)d_out, nullptr);

  (void)in_sizes; (void)n_in; (void)out_size; (void)ws_size;
}

// Round 4
// 353.690 us; speedup vs baseline: 1.4978x; 1.2479x over previous
//
#include <hip/hip_runtime.h>

// ---------------------------------------------------------------------------
// TransformerBlockQuantum: B=2,S=2048,E=1024,H=32,DK=32,FFN=4096
// GEMMs: bf16 MFMA 16x16x32 (m97 structure), fused QKV projection.
// Attention: swapped 32x32 QK^T, in-register softmax (permlane32_swap),
// split-K 2-way with LDS merge.
// permlane32_swap semantics: vdst_HI <-> vsrc_LO; vdst must be the LOW-key
// word (keys 2i,2i+1), vsrc the HIGH-key word (keys 8+2i,8+2i+1).
// ws layout (MB):
//  [0,2)WqT [2,4)WkT [4,6)WvT  (contiguous => fused QKV BT[3072][1024])
//  [6,8)WoT [8,16)W1T [16,24)W2T
//  [24,40) r1 (fp32 residual1 / post-LN1 fp32)
//  [40,48) xb  | [48,56) qh | [56,64) kh | [64,72) vT   <- hf aliases [40,72)
//  [72,80) ao  | [80,88) x1b                             <- r2 aliases [72,88)
// ---------------------------------------------------------------------------

typedef unsigned short u16;
typedef unsigned int u32;
typedef __bf16 bf16x8 __attribute__((ext_vector_type(8)));
typedef float f32x4 __attribute__((ext_vector_type(4)));
typedef float f32x16 __attribute__((ext_vector_type(16)));

__device__ __forceinline__ u16 f2b(float f) {
  union { float f; unsigned u; } x; x.f = f;
  unsigned r = x.u + 0x7FFFu + ((x.u >> 16) & 1u);
  return (u16)(r >> 16);
}

__device__ __forceinline__ unsigned pkbf(float lo, float hi) {
  unsigned r;
  asm("v_cvt_pk_bf16_f32 %0, %1, %2" : "=v"(r) : "v"(lo), "v"(hi));
  return r;
}

__device__ __forceinline__ float expo2(float x) {
#if __has_builtin(__builtin_amdgcn_exp2f)
  return __builtin_amdgcn_exp2f(x);
#else
  return exp2f(x);
#endif
}

#define GLDS16(gp, lp)                                                         \
  __builtin_amdgcn_global_load_lds(                                            \
      (const __attribute__((address_space(1))) void*)(gp),                     \
      (__attribute__((address_space(3))) void*)(lp), 16, 0, 0)

// ---------------- transpose + cast: W[K][N] f32 -> WT[N][K] bf16 ------------
__global__ __launch_bounds__(256) void transpose_cast(
    const float* __restrict__ W, u16* __restrict__ WT, int K, int N) {
  __shared__ float tile[32][33];
  const int tx = threadIdx.x & 31, ty = threadIdx.x >> 5;
  const int n0 = blockIdx.x * 32, k0 = blockIdx.y * 32;
#pragma unroll
  for (int i = 0; i < 4; ++i)
    tile[ty + 8 * i][tx] = W[(size_t)(k0 + ty + 8 * i) * N + n0 + tx];
  __syncthreads();
#pragma unroll
  for (int i = 0; i < 4; ++i)
    WT[(size_t)(n0 + ty + 8 * i) * K + k0 + tx] = f2b(tile[tx][ty + 8 * i]);
}

// ---------------- cast f32 -> bf16 (4 elems/thread) -------------------------
__global__ __launch_bounds__(256) void cast_b(const float* __restrict__ x,
                                              u16* __restrict__ y) {
  int i = blockIdx.x * 256 + threadIdx.x;
  float4 v = ((const float4*)x)[i];
  ushort4 o;
  o.x = f2b(v.x); o.y = f2b(v.y); o.z = f2b(v.z); o.w = f2b(v.w);
  ((ushort4*)y)[i] = o;
}

// ---------------- GEMM: C = A[M,K] @ BT[N,K]^T, bf16 in, fused epilogues ----
// MODE 2: fp32 out = acc + bias + res   (Wo and W2 paths)
// MODE 3: bf16 out = relu(acc + bias)   (W1 path)
// MODE 5: fused QKV: col<1024 -> q-scaled head store; <2048 -> k head store;
//         else -> v transposed store. bias/bias2/bias3 = bq/bk/bv.
template <int MODE>
__global__ __launch_bounds__(256) void gemm128(
    const u16* __restrict__ A, const u16* __restrict__ BT,
    const float* __restrict__ bias, const float* __restrict__ bias2,
    const float* __restrict__ bias3, const float* __restrict__ res,
    void* __restrict__ outp, const float* __restrict__ kW, int N_, int K_) {
  __shared__ __align__(16) u16 As[128 * 32];
  __shared__ __align__(16) u16 Bs[128 * 32];
  const int t = threadIdx.x;
  const int lane = t & 63, wid = t >> 6;
  const int m0 = blockIdx.y * 128, n0 = blockIdx.x * 128;
  const int wr = (wid >> 1) * 64, wc = (wid & 1) * 64;
  const int lr = lane & 15, lg = lane >> 4;
  const int K = K_;

  f32x4 acc[4][4] = {};

  const u16* ga0 = A + (size_t)(m0 + (t >> 2)) * K + (t & 3) * 8;
  const u16* ga1 = ga0 + (size_t)64 * K;
  const u16* gb0 = BT + (size_t)(n0 + (t >> 2)) * K + (t & 3) * 8;
  const u16* gb1 = gb0 + (size_t)64 * K;
  char* lA = (char*)As + wid * 1024;
  char* lB = (char*)Bs + wid * 1024;

  const int nk = K >> 5;
  for (int kt = 0; kt < nk; ++kt) {
    __syncthreads();
    GLDS16(ga0, lA); GLDS16(ga1, lA + 4096);
    GLDS16(gb0, lB); GLDS16(gb1, lB + 4096);
    ga0 += 32; ga1 += 32; gb0 += 32; gb1 += 32;
    __syncthreads();
    bf16x8 af[4], bf[4];
#pragma unroll
    for (int i = 0; i < 4; ++i) {
      af[i] = *(const bf16x8*)((const char*)As + (wr + i * 16 + lr) * 64 + lg * 16);
      bf[i] = *(const bf16x8*)((const char*)Bs + (wc + i * 16 + lr) * 64 + lg * 16);
    }
#pragma unroll
    for (int mi = 0; mi < 4; ++mi)
#pragma unroll
      for (int ni = 0; ni < 4; ++ni)
        acc[mi][ni] = __builtin_amdgcn_mfma_f32_16x16x32_bf16(
            af[mi], bf[ni], acc[mi][ni], 0, 0, 0);
  }

#pragma unroll
  for (int mi = 0; mi < 4; ++mi) {
#pragma unroll
    for (int ni = 0; ni < 4; ++ni) {
      const int row = m0 + wr + mi * 16 + lg * 4;
      const int col = n0 + wc + ni * 16 + lr;
      f32x4 v = acc[mi][ni];
      if constexpr (MODE == 2) {
        const float bv = bias[col];
        float* o = (float*)outp;
#pragma unroll
        for (int r = 0; r < 4; ++r) {
          const int rr = row + r;
          o[(size_t)rr * N_ + col] = v[r] + bv + res[(size_t)rr * N_ + col];
        }
      } else if constexpr (MODE == 3) {
        const float bv = bias[col];
        u16* o = (u16*)outp;
#pragma unroll
        for (int r = 0; r < 4; ++r) {
          const int rr = row + r;
          float y = v[r] + bv;
          o[(size_t)rr * N_ + col] = f2b(y > 0.f ? y : 0.f);
        }
      } else {  // MODE 5
        const int proj = col >> 10, c = col & 1023;
        const int h = c >> 5, d = c & 31;
        u16* qout = (u16*)outp;
        if (proj == 0) {
          const float bv = bias[c];
          const float sc = kW[d * 32 + h] * 1.44269504089f;
#pragma unroll
          for (int r = 0; r < 4; ++r) {
            const int rr = row + r;
            const int bb = rr >> 11, s = rr & 2047;
            qout[(size_t)(((bb * 32 + h) * 2048) + s) * 32 + d] =
                f2b((v[r] + bv) * sc);
          }
        } else if (proj == 1) {
          const float bv = bias2[c];
          u16* kout = qout + 4194304;
#pragma unroll
          for (int r = 0; r < 4; ++r) {
            const int rr = row + r;
            const int bb = rr >> 11, s = rr & 2047;
            kout[(size_t)(((bb * 32 + h) * 2048) + s) * 32 + d] =
                f2b(v[r] + bv);
          }
        } else {
          const float bv = bias3[c];
          u16* vout = qout + 8388608;
          const int bb = row >> 11, s0 = row & 2047;
          ushort4 st;
          st.x = f2b(v[0] + bv); st.y = f2b(v[1] + bv);
          st.z = f2b(v[2] + bv); st.w = f2b(v[3] + bv);
          *(ushort4*)(vout + ((size_t)((bb * 32 + h) * 32 + d)) * 2048 + s0) = st;
        }
      }
    }
  }
}

// ---------------- swapped 32x32 flash attention, split-K 2-way --------------
// Block = 4 waves: qg = wid&1 (32 queries each), kh = wid>>1 (1024 keys each).
// Scores pre-scaled by log2e (folded into q-proj). C[key][q]: lane holds 32
// scores of query lane&31 per 64-key batch. P->PV frag via cvt_pk+permlane.
__global__ __launch_bounds__(256) void attn_kernel(
    const u16* __restrict__ Q, const u16* __restrict__ K,
    const u16* __restrict__ VT, u16* __restrict__ O) {
  __shared__ float sm_m[2][32], sm_l[2][32];
  __shared__ float sm_acc[2][64][16];
  const int t = threadIdx.x, wid = t >> 6, lane = t & 63;
  const int qg = wid & 1, kh = wid >> 1;
  const int bid = blockIdx.x;
  const int swz = (bid & 7) * 256 + (bid >> 3);  // 2048 blocks, 8 XCDs
  const int bh = swz >> 5;                       // 0..63
  const int qt = swz & 31;                       // q-tile of 64
  const int q0 = qt * 64 + qg * 32;
  const int lq = lane & 31, hi = lane >> 5;
  const u16* Qh = Q + (size_t)bh * 2048 * 32;
  const u16* Kh = K + (size_t)bh * 2048 * 32;
  const u16* Vh = VT + (size_t)bh * 32 * 2048;

  bf16x8 qb[2];
  qb[0] = *(const bf16x8*)(Qh + (size_t)(q0 + lq) * 32 + hi * 8);
  qb[1] = *(const bf16x8*)(Qh + (size_t)(q0 + lq) * 32 + 16 + hi * 8);

  f32x16 acc = {};
  float mrun = -3e38f, lrun = 0.f;
  const f32x16 zero16 = {};

  const int jb = kh * 1024, je = jb + 1024;
  for (int j0 = jb; j0 < je; j0 += 64) {
    // K as A-operand: row=key (lane&31), k=dk chunk (8*hi..)
    f32x16 s[2];
#pragma unroll
    for (int sub = 0; sub < 2; ++sub) {
      const u16* kr = Kh + (size_t)(j0 + sub * 32 + lq) * 32 + hi * 8;
      const bf16x8 ka0 = *(const bf16x8*)(kr);
      const bf16x8 ka1 = *(const bf16x8*)(kr + 16);
      f32x16 c = __builtin_amdgcn_mfma_f32_32x32x16_bf16(ka0, qb[0], zero16, 0, 0, 0);
      s[sub] = __builtin_amdgcn_mfma_f32_32x32x16_bf16(ka1, qb[1], c, 0, 0, 0);
    }
    // per-query max: 31 local + one cross-half hop
    float mx = s[0][0];
#pragma unroll
    for (int r = 1; r < 16; ++r) mx = fmaxf(mx, s[0][r]);
#pragma unroll
    for (int r = 0; r < 16; ++r) mx = fmaxf(mx, s[1][r]);
    mx = fmaxf(mx, __shfl_xor(mx, 32));
    if (!__all(mx <= mrun + 8.f)) {  // T13 defer-max
      const float mn = fmaxf(mrun, mx);
      const float al = expo2(mrun - mn);
      mrun = mn;
      lrun *= al;
#pragma unroll
      for (int r = 0; r < 16; ++r) acc[r] *= al;
    }
    // exp + sum + pack to PV B-fragments
    float sm = 0.f;
    bf16x8 pb[2][2];
#pragma unroll
    for (int sub = 0; sub < 2; ++sub) {
      float p[16];
#pragma unroll
      for (int r = 0; r < 16; ++r) { p[r] = expo2(s[sub][r] - mrun); sm += p[r]; }
#pragma unroll
      for (int c = 0; c < 2; ++c) {
        // x* = low-key words (regs 0-3 -> keys 0-3(+4hi)), y* = high-key
        // words (regs 4-7 -> keys 8-11(+4hi)). Swap vdst_HI <-> vsrc_LO with
        // vdst = x (low keys): after swap x = {keys 2i,2i+1 | keys 8+2i,..},
        // y = {keys 4+2i,.. | keys 12+2i,..} -> words 0,1,2,3 = x0,x1,y0,y1.
        u32 x0 = pkbf(p[c * 8 + 0], p[c * 8 + 1]);
        u32 x1 = pkbf(p[c * 8 + 2], p[c * 8 + 3]);
        u32 y0 = pkbf(p[c * 8 + 4], p[c * 8 + 5]);
        u32 y1 = pkbf(p[c * 8 + 6], p[c * 8 + 7]);
        asm volatile("v_permlane32_swap_b32 %0, %1" : "+v"(x0), "+v"(y0));
        asm volatile("v_permlane32_swap_b32 %0, %1" : "+v"(x1), "+v"(y1));
        union { u32 d[4]; bf16x8 v; } u;
        u.d[0] = x0; u.d[1] = x1; u.d[2] = y0; u.d[3] = y1;
        pb[sub][c] = u.v;
      }
    }
    sm += __shfl_xor(sm, 32);
    lrun += sm;
    // PV: V^T as A-operand (row=d, k=key)
#pragma unroll
    for (int sub = 0; sub < 2; ++sub)
#pragma unroll
      for (int c = 0; c < 2; ++c) {
        const bf16x8 va = *(const bf16x8*)(Vh + (size_t)lq * 2048 + j0 +
                                           sub * 32 + c * 16 + hi * 8);
        acc = __builtin_amdgcn_mfma_f32_32x32x16_bf16(va, pb[sub][c], acc, 0, 0, 0);
      }
  }

  // merge the two key-halves via LDS
  if (kh == 1) {
    sm_m[qg][lq] = mrun;
    sm_l[qg][lq] = lrun;
#pragma unroll
    for (int r = 0; r < 16; ++r) sm_acc[qg][lane][r] = acc[r];
  }
  __syncthreads();
  if (kh == 0) {
    const float m1 = sm_m[qg][lq], l1 = sm_l[qg][lq];
    const float mT = fmaxf(mrun, m1);
    const float a0 = expo2(mrun - mT), a1 = expo2(m1 - mT);
    const float inv = 1.f / (lrun * a0 + l1 * a1);
    const int bb = bh >> 5, h = bh & 31;
    u16* o = O + (size_t)(bb * 2048 + q0 + lq) * 1024 + h * 32;
#pragma unroll
    for (int g = 0; g < 4; ++g) {
      ushort4 st;
      st.x = f2b((acc[g * 4 + 0] * a0 + sm_acc[qg][lane][g * 4 + 0] * a1) * inv);
      st.y = f2b((acc[g * 4 + 1] * a0 + sm_acc[qg][lane][g * 4 + 1] * a1) * inv);
      st.z = f2b((acc[g * 4 + 2] * a0 + sm_acc[qg][lane][g * 4 + 2] * a1) * inv);
      st.w = f2b((acc[g * 4 + 3] * a0 + sm_acc[qg][lane][g * 4 + 3] * a1) * inv);
      *(ushort4*)(o + g * 8 + hi * 4) = st;
    }
  }
}

// ---------------- LayerNorm (1 wave per row of 1024) ------------------------
template <int WB>
__global__ __launch_bounds__(256) void ln_kernel(
    const float* X, const float* __restrict__ g, const float* __restrict__ b,
    float* outf, u16* __restrict__ outb) {
  const int wid = threadIdx.x >> 6, lane = threadIdx.x & 63;
  const int row = blockIdx.x * 4 + wid;
  const float4* X4 = (const float4*)(X + (size_t)row * 1024);
  float4 xs[4];
  float s = 0.f, sq = 0.f;
#pragma unroll
  for (int i = 0; i < 4; ++i) {
    xs[i] = X4[lane + i * 64];
    s += xs[i].x + xs[i].y + xs[i].z + xs[i].w;
    sq += xs[i].x * xs[i].x + xs[i].y * xs[i].y + xs[i].z * xs[i].z + xs[i].w * xs[i].w;
  }
#pragma unroll
  for (int m = 1; m < 64; m <<= 1) { s += __shfl_xor(s, m); sq += __shfl_xor(sq, m); }
  const float mean = s * (1.f / 1024.f);
  float var = sq * (1.f / 1024.f) - mean * mean;
  var = var > 0.f ? var : 0.f;
  const float rstd = rsqrtf(var + 1e-5f);
  const float4* g4 = (const float4*)g;
  const float4* b4 = (const float4*)b;
  float4* of = (float4*)(outf + (size_t)row * 1024);
#pragma unroll
  for (int i = 0; i < 4; ++i) {
    const int c = lane + i * 64;
    const float4 gv = g4[c], bv = b4[c], x = xs[i];
    float4 y;
    y.x = (x.x - mean) * rstd * gv.x + bv.x;
    y.y = (x.y - mean) * rstd * gv.y + bv.y;
    y.z = (x.z - mean) * rstd * gv.z + bv.z;
    y.w = (x.w - mean) * rstd * gv.w + bv.w;
    of[c] = y;
    if constexpr (WB) {
      ushort4 yb;
      yb.x = f2b(y.x); yb.y = f2b(y.y); yb.z = f2b(y.z); yb.w = f2b(y.w);
      ((ushort4*)(outb + (size_t)row * 1024))[c] = yb;
    }
  }
}

// ---------------------------------------------------------------------------
extern "C" void kernel_launch(void* const* d_in, const int* in_sizes, int n_in,
                              void* d_out, int out_size, void* d_ws,
                              size_t ws_size, hipStream_t stream) {
  const float* x   = (const float*)d_in[0];
  const float* Wq  = (const float*)d_in[1];
  const float* bq  = (const float*)d_in[2];
  const float* Wk  = (const float*)d_in[3];
  const float* bk  = (const float*)d_in[4];
  const float* Wv  = (const float*)d_in[5];
  const float* bv  = (const float*)d_in[6];
  const float* kW  = (const float*)d_in[7];
  const float* Wo  = (const float*)d_in[8];
  const float* bo  = (const float*)d_in[9];
  const float* W1  = (const float*)d_in[10];
  const float* b1  = (const float*)d_in[11];
  const float* W2  = (const float*)d_in[12];
  const float* b2  = (const float*)d_in[13];
  const float* g1  = (const float*)d_in[14];
  const float* be1 = (const float*)d_in[15];
  const float* g2  = (const float*)d_in[16];
  const float* be2 = (const float*)d_in[17];

  char* ws = (char*)d_ws;
  const size_t MB = 1024 * 1024;
  u16*   WqT = (u16*)(ws + 0 * MB);   // [0,6) = fused QKV BT[3072][1024]
  u16*   WkT = (u16*)(ws + 2 * MB);
  u16*   WvT = (u16*)(ws + 4 * MB);
  u16*   WoT = (u16*)(ws + 6 * MB);
  u16*   W1T = (u16*)(ws + 8 * MB);
  u16*   W2T = (u16*)(ws + 16 * MB);
  float* r1  = (float*)(ws + 24 * MB);
  u16*   xb  = (u16*)(ws + 40 * MB);
  u16*   qhB = (u16*)(ws + 48 * MB);
  u16*   khB = (u16*)(ws + 56 * MB);
  u16*   vTB = (u16*)(ws + 64 * MB);
  u16*   hf  = (u16*)(ws + 40 * MB);  // aliases xb..vT, free by then
  u16*   ao  = (u16*)(ws + 72 * MB);
  u16*   x1b = (u16*)(ws + 80 * MB);
  float* r2  = (float*)(ws + 72 * MB);  // aliases ao+x1b, free by then

  const dim3 blk(256);

  transpose_cast<<<dim3(32, 32), blk, 0, stream>>>(Wq, WqT, 1024, 1024);
  transpose_cast<<<dim3(32, 32), blk, 0, stream>>>(Wk, WkT, 1024, 1024);
  transpose_cast<<<dim3(32, 32), blk, 0, stream>>>(Wv, WvT, 1024, 1024);
  transpose_cast<<<dim3(32, 32), blk, 0, stream>>>(Wo, WoT, 1024, 1024);
  transpose_cast<<<dim3(128, 32), blk, 0, stream>>>(W1, W1T, 1024, 4096);
  transpose_cast<<<dim3(32, 128), blk, 0, stream>>>(W2, W2T, 4096, 1024);
  cast_b<<<4096, blk, 0, stream>>>(x, xb);

  // fused QKV projection (q scaled by kernelW*log2e, v stored transposed)
  gemm128<5><<<dim3(24, 32), blk, 0, stream>>>(xb, WqT, bq, bk, bv, nullptr,
                                               qhB, kW, 3072, 1024);

  // flash attention: 2048 blocks x 4 waves (2 qg x 2 key-halves)
  attn_kernel<<<2048, blk, 0, stream>>>(qhB, khB, vTB, ao);

  // out-proj + residual -> r1 (fp32)
  gemm128<2><<<dim3(8, 32), blk, 0, stream>>>(ao, WoT, bo, nullptr, nullptr, x,
                                              r1, nullptr, 1024, 1024);
  ln_kernel<1><<<1024, blk, 0, stream>>>(r1, g1, be1, r1, x1b);
  // FFN
  gemm128<3><<<dim3(32, 32), blk, 0, stream>>>(x1b, W1T, b1, nullptr, nullptr,
                                               nullptr, hf, nullptr, 4096, 1024);
  gemm128<2><<<dim3(8, 32), blk, 0, stream>>>(hf, W2T, b2, nullptr, nullptr, r1,
                                              r2, nullptr, 1024, 4096);
  ln_kernel<0><<<1024, blk, 0, stream>>>(r2, g2, be2, (float*)d_out, nullptr);

  (void)in_sizes; (void)n_in; (void)out_size; (void)ws_size;
}